// Round 1
// baseline (430.285 us; speedup 1.0000x reference)
//
#include <hip/hip_runtime.h>
#include <stdint.h>

#define NN 40000
#define NE 640000
#define ND 128
#define ED 64
#define OD 128
#define KM 192   // ND + ED
#define KA 256   // ND + OD

typedef __attribute__((ext_vector_type(8))) short bf16x8;
typedef __attribute__((ext_vector_type(4))) float f32x4;
typedef __attribute__((ext_vector_type(4))) unsigned short us4;

__device__ __forceinline__ unsigned short f2bf(float f) {
    union { float f; uint32_t u; } v; v.f = f;
    return (unsigned short)((v.u + 0x7fffu + ((v.u >> 16) & 1u)) >> 16);
}
__device__ __forceinline__ us4 pk4(float4 v) {
    us4 r; r.x = f2bf(v.x); r.y = f2bf(v.y); r.z = f2bf(v.z); r.w = f2bf(v.w);
    return r;
}

// ---------------- message + atomic aggregate ----------------
// Per block: 32 edges. GEMM [32 x 192] x [192 x 128] via 16x16x32 bf16 MFMA.
// 4 waves; each wave computes all 32 edge-rows x 32 output cols.
#define MT 32
#define LK (KM + 8)   // 200 bf16 elems/row -> 400 B row stride (bank step 4)

__global__ __launch_bounds__(256, 2) void msg_kernel(
    const float* __restrict__ node, const float* __restrict__ edgef,
    const int* __restrict__ src, const int* __restrict__ dst,
    const float* __restrict__ Wm, const float* __restrict__ bm,
    float* __restrict__ hn)
{
    __shared__ unsigned short sW[OD][LK];  // 51200 B, W[n][k] (B operand, K x N logical)
    __shared__ unsigned short sA[MT][LK];  // 12800 B, concat(node[src], edge) per edge

    const int t  = threadIdx.x;
    const int e0 = blockIdx.x * MT;

    // stage weights 128x192 fp32 -> bf16 (float4 -> us4)
    for (int i = t; i < OD * KM / 4; i += 256) {
        int base = i * 4;
        int n = base / KM, k = base % KM;
        float4 w = *(const float4*)(Wm + n * KM + k);
        *(us4*)&sW[n][k] = pk4(w);
    }
    // stage activations: 8 threads per edge
    {
        int el = t >> 3, sub = t & 7;
        int s = src[e0 + el];
        const float* np = node + (size_t)s * ND + sub * 16;
        #pragma unroll
        for (int i = 0; i < 4; ++i) {
            float4 v = *(const float4*)(np + i * 4);
            *(us4*)&sA[el][sub * 16 + i * 4] = pk4(v);
        }
        const float* ep = edgef + (size_t)(e0 + el) * ED + sub * 8;
        #pragma unroll
        for (int i = 0; i < 2; ++i) {
            float4 v = *(const float4*)(ep + i * 4);
            *(us4*)&sA[el][ND + sub * 8 + i * 4] = pk4(v);
        }
    }
    __syncthreads();

    const int w = t >> 6, lane = t & 63, l15 = lane & 15, lhi = lane >> 4;
    const int koff = lhi * 8;
    f32x4 acc[2][2] = {};

    #pragma unroll
    for (int ks = 0; ks < 6; ++ks) {
        bf16x8 a0 = *(const bf16x8*)&sA[l15][ks * 32 + koff];
        bf16x8 a1 = *(const bf16x8*)&sA[16 + l15][ks * 32 + koff];
        bf16x8 b0 = *(const bf16x8*)&sW[w * 32 + l15][ks * 32 + koff];
        bf16x8 b1 = *(const bf16x8*)&sW[w * 32 + 16 + l15][ks * 32 + koff];
        acc[0][0] = __builtin_amdgcn_mfma_f32_16x16x32_bf16(a0, b0, acc[0][0], 0, 0, 0);
        acc[1][0] = __builtin_amdgcn_mfma_f32_16x16x32_bf16(a1, b0, acc[1][0], 0, 0, 0);
        acc[0][1] = __builtin_amdgcn_mfma_f32_16x16x32_bf16(a0, b1, acc[0][1], 0, 0, 0);
        acc[1][1] = __builtin_amdgcn_mfma_f32_16x16x32_bf16(a1, b1, acc[1][1], 0, 0, 0);
    }

    // D[m][n]: m = ai*16 + 4*lhi + r, n = w*32 + bj*16 + l15
    #pragma unroll
    for (int ai = 0; ai < 2; ++ai) {
        #pragma unroll
        for (int r = 0; r < 4; ++r) {
            int el = ai * 16 + 4 * lhi + r;
            int d  = dst[e0 + el];
            float* hrow = hn + (size_t)d * OD;
            #pragma unroll
            for (int bj = 0; bj < 2; ++bj) {
                int n = w * 32 + bj * 16 + l15;
                float v = acc[ai][bj][r] + bm[n];
                v = v > 0.f ? v : 0.f;   // relu BEFORE aggregation
                atomicAdd(hrow + n, v);
            }
        }
    }
}

// ---------------- apply: relu([node | h_neigh] @ Wa^T + ba) ----------------
#define AT 32
#define LKA (KA + 8)   // 264
#define LKW (128 + 8)  // 136 (one 128-wide k-chunk of Wa)

__global__ __launch_bounds__(256, 2) void apply_kernel(
    const float* __restrict__ node, const float* __restrict__ hn,
    const float* __restrict__ Wa, const float* __restrict__ ba,
    float* __restrict__ out)
{
    __shared__ unsigned short sW[OD][LKW];  // 34816 B
    __shared__ unsigned short sA[AT][LKA];  // 16896 B

    const int t  = threadIdx.x;
    const int n0 = blockIdx.x * AT;

    // stage activations: [node(128) | h_neigh(128)] per node row
    {
        int el = t >> 3, sub = t & 7;
        const float* np = node + (size_t)(n0 + el) * ND + sub * 16;
        #pragma unroll
        for (int i = 0; i < 4; ++i) {
            float4 v = *(const float4*)(np + i * 4);
            *(us4*)&sA[el][sub * 16 + i * 4] = pk4(v);
        }
        const float* hp = hn + (size_t)(n0 + el) * OD + sub * 16;
        #pragma unroll
        for (int i = 0; i < 4; ++i) {
            float4 v = *(const float4*)(hp + i * 4);
            *(us4*)&sA[el][ND + sub * 16 + i * 4] = pk4(v);
        }
    }
    // stage Wa chunk 0: k in [0,128)
    for (int i = t; i < OD * 128 / 4; i += 256) {
        int base = i * 4;
        int n = base / 128, k = base % 128;
        float4 w = *(const float4*)(Wa + n * KA + k);
        *(us4*)&sW[n][k] = pk4(w);
    }
    __syncthreads();

    const int w = t >> 6, lane = t & 63, l15 = lane & 15, lhi = lane >> 4;
    const int koff = lhi * 8;
    f32x4 acc[2][2] = {};

    #pragma unroll
    for (int ks = 0; ks < 4; ++ks) {
        bf16x8 a0 = *(const bf16x8*)&sA[l15][ks * 32 + koff];
        bf16x8 a1 = *(const bf16x8*)&sA[16 + l15][ks * 32 + koff];
        bf16x8 b0 = *(const bf16x8*)&sW[w * 32 + l15][ks * 32 + koff];
        bf16x8 b1 = *(const bf16x8*)&sW[w * 32 + 16 + l15][ks * 32 + koff];
        acc[0][0] = __builtin_amdgcn_mfma_f32_16x16x32_bf16(a0, b0, acc[0][0], 0, 0, 0);
        acc[1][0] = __builtin_amdgcn_mfma_f32_16x16x32_bf16(a1, b0, acc[1][0], 0, 0, 0);
        acc[0][1] = __builtin_amdgcn_mfma_f32_16x16x32_bf16(a0, b1, acc[0][1], 0, 0, 0);
        acc[1][1] = __builtin_amdgcn_mfma_f32_16x16x32_bf16(a1, b1, acc[1][1], 0, 0, 0);
    }
    __syncthreads();  // all waves done with chunk 0 before overwrite
    // stage Wa chunk 1: k in [128,256)
    for (int i = t; i < OD * 128 / 4; i += 256) {
        int base = i * 4;
        int n = base / 128, k = base % 128;
        float4 w = *(const float4*)(Wa + n * KA + 128 + k);
        *(us4*)&sW[n][k] = pk4(w);
    }
    __syncthreads();
    #pragma unroll
    for (int ks = 0; ks < 4; ++ks) {
        bf16x8 a0 = *(const bf16x8*)&sA[l15][128 + ks * 32 + koff];
        bf16x8 a1 = *(const bf16x8*)&sA[16 + l15][128 + ks * 32 + koff];
        bf16x8 b0 = *(const bf16x8*)&sW[w * 32 + l15][ks * 32 + koff];
        bf16x8 b1 = *(const bf16x8*)&sW[w * 32 + 16 + l15][ks * 32 + koff];
        acc[0][0] = __builtin_amdgcn_mfma_f32_16x16x32_bf16(a0, b0, acc[0][0], 0, 0, 0);
        acc[1][0] = __builtin_amdgcn_mfma_f32_16x16x32_bf16(a1, b0, acc[1][0], 0, 0, 0);
        acc[0][1] = __builtin_amdgcn_mfma_f32_16x16x32_bf16(a0, b1, acc[0][1], 0, 0, 0);
        acc[1][1] = __builtin_amdgcn_mfma_f32_16x16x32_bf16(a1, b1, acc[1][1], 0, 0, 0);
    }

    #pragma unroll
    for (int ai = 0; ai < 2; ++ai) {
        #pragma unroll
        for (int r = 0; r < 4; ++r) {
            int nd = n0 + ai * 16 + 4 * lhi + r;
            #pragma unroll
            for (int bj = 0; bj < 2; ++bj) {
                int n = w * 32 + bj * 16 + l15;
                float v = acc[ai][bj][r] + ba[n];
                out[(size_t)nd * OD + n] = v > 0.f ? v : 0.f;
            }
        }
    }
}

extern "C" void kernel_launch(void* const* d_in, const int* in_sizes, int n_in,
                              void* d_out, int out_size, void* d_ws, size_t ws_size,
                              hipStream_t stream) {
    const float* node  = (const float*)d_in[0];
    const float* edgef = (const float*)d_in[1];
    const int*   src   = (const int*)d_in[2];
    const int*   dst   = (const int*)d_in[3];
    const float* Wm    = (const float*)d_in[4];
    const float* bm    = (const float*)d_in[5];
    const float* Wa    = (const float*)d_in[6];
    const float* ba    = (const float*)d_in[7];
    float* out = (float*)d_out;

    // h_neigh scratch: workspace if big enough, else reuse d_out (apply reads
    // its rows fully in the staging phase before any store to them).
    const size_t hn_bytes = (size_t)NN * OD * sizeof(float);
    float* hn = (ws_size >= hn_bytes) ? (float*)d_ws : out;

    hipMemsetAsync(hn, 0, hn_bytes, stream);
    msg_kernel<<<NE / MT, 256, 0, stream>>>(node, edgef, src, dst, Wm, bm, hn);
    apply_kernel<<<NN / AT, 256, 0, stream>>>(node, hn, Wa, ba, out);
}